// Round 9
// baseline (32.374 us; speedup 1.0000x reference)
//
#include <hip/hip_runtime.h>
#include <math.h>

typedef _Float16 h2 __attribute__((ext_vector_type(2)));
__device__ __forceinline__ h2 u2h(unsigned u) { return __builtin_bit_cast(h2, u); }
__device__ __forceinline__ unsigned h2u(h2 h) { return __builtin_bit_cast(unsigned, h); }

// ---- prepass: sigmoid -> fp16 rows (8B units) + row sums of rounded values ----
__global__ __launch_bounds__(256)
void prepass(const float* __restrict__ x1, const float* __restrict__ x2,
             uint2* __restrict__ Ah, uint2* __restrict__ Bh,
             float* __restrict__ rs) {
    const int wid = threadIdx.x >> 6, lane = threadIdx.x & 63;
    const int r = blockIdx.x * 4 + wid;            // 0..2047
    const bool isA = (r < 1024);
    const int row = isA ? r : (r - 1024);
    const float* src = (isA ? x1 : x2) + (size_t)row * 256;

    float4 g = *(const float4*)(src + 4 * lane);
    float4 s;
    s.x = 1.0f / (1.0f + __expf(-g.x));
    s.y = 1.0f / (1.0f + __expf(-g.y));
    s.z = 1.0f / (1.0f + __expf(-g.z));
    s.w = 1.0f / (1.0f + __expf(-g.w));
    h2 lo, hi;
    lo.x = (_Float16)s.x; lo.y = (_Float16)s.y;
    hi.x = (_Float16)s.z; hi.y = (_Float16)s.w;

    (isA ? Ah : Bh)[(size_t)row * 64 + lane] = make_uint2(h2u(lo), h2u(hi));

    float sum = ((float)lo.x + (float)lo.y) + ((float)hi.x + (float)hi.y);
    #pragma unroll
    for (int k = 32; k >= 1; k >>= 1)
        sum += __shfl_xor(sum, k, 64);
    if (lane == 0) rs[r] = sum;
}

// ---- main: LDS-free, barrier-free. Wave = 4 rows x 64 cols. ----
// Lane j holds B-row j's D-quarter in regs; A-row values are wave-uniform
// (scalar pipe); per-quarter h2 partial -> f32 accumulate (R8 error tree).
__global__ __launch_bounds__(256, 4)
void jaccard_main(const unsigned* __restrict__ Aw, const uint4* __restrict__ Bq,
                  const float* __restrict__ rs, float* __restrict__ out) {
    const int bi   = blockIdx.x;          // 0..63 : 16-row stripes
    const int bj   = blockIdx.y;          // 0..15 : 64-col stripes
    const int lane = threadIdx.x & 63;
    const int w    = threadIdx.x >> 6;    // 0..3

    const int j = bj * 64 + lane;                       // this lane's B row / out col
    const uint4* brow = Bq + (size_t)j * 32;            // 32 uint4 per 512B row

    const int row0 = __builtin_amdgcn_readfirstlane(bi * 16 + w * 4);

    float facc[4] = {0.f, 0.f, 0.f, 0.f};

    #pragma unroll
    for (int q = 0; q < 4; ++q) {                       // D-quarter = 64 halfs
        uint4 bq[8];
        #pragma unroll
        for (int k = 0; k < 8; ++k) bq[k] = brow[q * 8 + k];   // 32 VGPRs

        #pragma unroll
        for (int r = 0; r < 4; ++r) {
            const unsigned* aw = Aw + (size_t)(row0 + r) * 128 + q * 32;  // uniform
            h2 acc = {0, 0};
            #pragma unroll
            for (int k = 0; k < 8; ++k) {
                h2 m0 = __builtin_elementwise_min(u2h(bq[k].x), u2h(aw[4 * k + 0]));
                h2 m1 = __builtin_elementwise_min(u2h(bq[k].y), u2h(aw[4 * k + 1]));
                h2 m2 = __builtin_elementwise_min(u2h(bq[k].z), u2h(aw[4 * k + 2]));
                h2 m3 = __builtin_elementwise_min(u2h(bq[k].w), u2h(aw[4 * k + 3]));
                acc += (m0 + m1) + (m2 + m3);
            }
            facc[r] += (float)acc.x + (float)acc.y;
        }
    }

    const float sb = rs[1024 + j];
    float* outT = out + (size_t)1024 * 1024;

    #pragma unroll
    for (int r = 0; r < 4; ++r) {
        const int i = row0 + r;
        const float sa = rs[i];
        const float I = facc[r];
        const float v = I / (sa + sb - I);
        out [(size_t)i * 1024 + j] = v;        // coalesced over lanes
        outT[(size_t)j * 1024 + i] = v;        // scatter; L2 merges sectors
    }
}

extern "C" void kernel_launch(void* const* d_in, const int* in_sizes, int n_in,
                              void* d_out, int out_size, void* d_ws, size_t ws_size,
                              hipStream_t stream) {
    const float* x1 = (const float*)d_in[0];
    const float* x2 = (const float*)d_in[1];
    float* out = (float*)d_out;

    uint2* Ah = (uint2*)d_ws;                       // 512 KB
    uint2* Bh = Ah + (size_t)1024 * 64;             // 512 KB
    float* rs = (float*)(Bh + (size_t)1024 * 64);   // 2048 floats

    prepass<<<512, 256, 0, stream>>>(x1, x2, Ah, Bh, rs);
    jaccard_main<<<dim3(64, 16), 256, 0, stream>>>((const unsigned*)Ah, (const uint4*)Bh,
                                                   rs, out);
}

// Round 10
// 18.790 us; speedup vs baseline: 1.7230x; 1.7230x over previous
//
#include <hip/hip_runtime.h>
#include <math.h>

#define BM    64
#define RSTR  272                  // u8 row stride in LDS bytes (16B-aligned, 68 dwords)
#define AOFF  0
#define BOFF  (BM * RSTR)          // 17408
#define POFF  (2 * BM * RSTR)      // 34816: partials, 1024 thr x 72 B
#define PSTR  72
#define LDSZ  (POFF + 1024 * PSTR) // 108544 B

// v_sad_u8: d = c + sum_k |a.byte[k] - b.byte[k]|  (4 elems + accumulate, 1 instr)
__device__ __forceinline__ unsigned sad8(unsigned a, unsigned b, unsigned c) {
    unsigned d;
    asm("v_sad_u8 %0, %1, %2, %3" : "=v"(d) : "v"(a), "v"(b), "v"(c));
    return d;
}

// ---- prepass: sigmoid -> u8 (x255, round) + integer row sums (exact in f32) ----
__global__ __launch_bounds__(256)
void prepass(const float* __restrict__ x1, const float* __restrict__ x2,
             unsigned* __restrict__ Aq, unsigned* __restrict__ Bq,
             float* __restrict__ rs) {
    const int wid = threadIdx.x >> 6, lane = threadIdx.x & 63;
    const int r = blockIdx.x * 4 + wid;            // 0..2047
    const bool isA = (r < 1024);
    const int row = isA ? r : (r - 1024);
    const float* src = (isA ? x1 : x2) + (size_t)row * 256;

    float4 g = *(const float4*)(src + 4 * lane);
    const float k = 255.0f;
    unsigned q0 = (unsigned)(k / (1.0f + __expf(-g.x)) + 0.5f);
    unsigned q1 = (unsigned)(k / (1.0f + __expf(-g.y)) + 0.5f);
    unsigned q2 = (unsigned)(k / (1.0f + __expf(-g.z)) + 0.5f);
    unsigned q3 = (unsigned)(k / (1.0f + __expf(-g.w)) + 0.5f);

    (isA ? Aq : Bq)[(size_t)row * 64 + lane] = q0 | (q1 << 8) | (q2 << 16) | (q3 << 24);

    int sum = (int)(q0 + q1 + q2 + q3);
    #pragma unroll
    for (int s = 32; s >= 1; s >>= 1)
        sum += __shfl_xor(sum, s, 64);
    if (lane == 0) rs[r] = (float)sum;             // <= 65280: f32-exact
}

// ---- main: copy staging, 4x4 microtile, D quarters, SAD inner loop ----
__global__ __launch_bounds__(1024, 4)
void jaccard_main(const unsigned* __restrict__ Aq, const unsigned* __restrict__ Bq,
                  const float* __restrict__ rs, float* __restrict__ out) {
    extern __shared__ char lds[];
    char* ATile = lds + AOFF;
    char* BTile = lds + BOFF;
    char* Part  = lds + POFF;

    const int bi = blockIdx.x, bj = blockIdx.y;
    const int tid = threadIdx.x;

    // ---- staging: pure u8 copy, 32 KB total, uint2 units ----
    #pragma unroll
    for (int k = 0; k < 2; ++k) {
        const int flat = tid + 1024 * k;           // 0..2047
        const int row = flat >> 5, u2i = flat & 31;
        uint2 va = *(const uint2*)(Aq + (size_t)(bi * BM + row) * 64 + 2 * u2i);
        *(uint2*)(ATile + row * RSTR + u2i * 8) = va;
        uint2 vb = *(const uint2*)(Bq + (size_t)(bj * BM + row) * 64 + 2 * u2i);
        *(uint2*)(BTile + row * RSTR + u2i * 8) = vb;
    }
    __syncthreads();

    const int s  = tid & 255;
    const int q  = tid >> 8;       // D-quarter: bytes [64q, 64q+64)
    const int tx = s & 15;         // cols {tx + 16n}
    const int ty = s >> 4;         // rows {ty + 16m}

    const char* ab = ATile + ty * RSTR + q * 64;
    const char* bb = BTile + tx * RSTR + q * 64;

    unsigned acc[4][4] = {};       // SAD accumulators (u32)
    #pragma unroll
    for (int cc = 0; cc < 4; ++cc) {               // 4 x 16B chunks per quarter
        uint4 av[4], bv[4];
        #pragma unroll
        for (int m = 0; m < 4; ++m)
            av[m] = *(const uint4*)(ab + m * (16 * RSTR) + cc * 16);
        #pragma unroll
        for (int n = 0; n < 4; ++n)
            bv[n] = *(const uint4*)(bb + n * (16 * RSTR) + cc * 16);
        #pragma unroll
        for (int m = 0; m < 4; ++m)
            #pragma unroll
            for (int n = 0; n < 4; ++n) {
                unsigned a = acc[m][n];
                a = sad8(av[m].x, bv[n].x, a);
                a = sad8(av[m].y, bv[n].y, a);
                a = sad8(av[m].z, bv[n].z, a);
                a = sad8(av[m].w, bv[n].w, a);
                acc[m][n] = a;
            }
    }

    char* pw = Part + (size_t)(q * 256 + s) * PSTR;
    #pragma unroll
    for (int m = 0; m < 4; ++m)
        *(uint4*)(pw + m * 16) = make_uint4(acc[m][0], acc[m][1], acc[m][2], acc[m][3]);
    __syncthreads();

    // epilogue: thread (s,q) owns row ty+16q, cols {tx+16n}
    unsigned sd0 = 0, sd1 = 0, sd2 = 0, sd3 = 0;
    #pragma unroll
    for (int qq = 0; qq < 4; ++qq) {
        uint4 p = *(const uint4*)(Part + (size_t)(qq * 256 + s) * PSTR + q * 16);
        sd0 += p.x; sd1 += p.y; sd2 += p.z; sd3 += p.w;
    }

    const int i  = bi * 64 + ty + 16 * q;
    const int j0 = bj * 64 + tx;

    const float sa  = rs[i];
    const float sb0 = rs[1024 + j0];
    const float sb1 = rs[1024 + j0 + 16];
    const float sb2 = rs[1024 + j0 + 32];
    const float sb3 = rs[1024 + j0 + 48];

    // inter = (sa + sb - sad)/2 ; union = sa + sb - inter ; all f32-exact ints
    const float t0 = sa + sb0, t1 = sa + sb1, t2 = sa + sb2, t3 = sa + sb3;
    const float i0 = 0.5f * (t0 - (float)sd0);
    const float i1 = 0.5f * (t1 - (float)sd1);
    const float i2 = 0.5f * (t2 - (float)sd2);
    const float i3 = 0.5f * (t3 - (float)sd3);
    const float v0 = i0 / (t0 - i0);
    const float v1 = i1 / (t1 - i1);
    const float v2 = i2 / (t2 - i2);
    const float v3 = i3 / (t3 - i3);

    float* outT = out + (size_t)1024 * 1024;
    out[(size_t)i * 1024 + j0]      = v0;
    out[(size_t)i * 1024 + j0 + 16] = v1;
    out[(size_t)i * 1024 + j0 + 32] = v2;
    out[(size_t)i * 1024 + j0 + 48] = v3;
    outT[(size_t)j0        * 1024 + i] = v0;
    outT[(size_t)(j0 + 16) * 1024 + i] = v1;
    outT[(size_t)(j0 + 32) * 1024 + i] = v2;
    outT[(size_t)(j0 + 48) * 1024 + i] = v3;
}

extern "C" void kernel_launch(void* const* d_in, const int* in_sizes, int n_in,
                              void* d_out, int out_size, void* d_ws, size_t ws_size,
                              hipStream_t stream) {
    const float* x1 = (const float*)d_in[0];
    const float* x2 = (const float*)d_in[1];
    float* out = (float*)d_out;

    unsigned* Aq = (unsigned*)d_ws;                 // 256 KB
    unsigned* Bq = Aq + (size_t)1024 * 64;          // 256 KB
    float*    rs = (float*)(Bq + (size_t)1024 * 64);// 8 KB

    hipFuncSetAttribute((const void*)jaccard_main,
                        hipFuncAttributeMaxDynamicSharedMemorySize, LDSZ);

    prepass<<<512, 256, 0, stream>>>(x1, x2, Aq, Bq, rs);
    jaccard_main<<<dim3(16, 16), 1024, LDSZ, stream>>>(Aq, Bq, rs, out);
}